// Round 1
// baseline (1539.752 us; speedup 1.0000x reference)
//
#include <hip/hip_runtime.h>

#define N_NODES 100000
#define N_EDGES 1600000
#define F_IN    128
#define HID     64
#define N_CLASS 40
#define NEG_SLOPE 0.2f

// ---------------------------------------------------------------------------
// h0 = relu(x @ W1 + b1)   [N,128] @ [128,64]
// One wave per row: lane = output col. W1 staged in LDS (32 KB).
// Row broadcast via __shfl of the two 64-chunks each lane loaded.
// ---------------------------------------------------------------------------
__global__ __launch_bounds__(256) void k_lin1(const float* __restrict__ x,
        const float* __restrict__ W1, const float* __restrict__ b1,
        float* __restrict__ out) {
    __shared__ float Ws[F_IN * HID];          // 32 KB
    int tid = threadIdx.x;
    for (int i = tid; i < F_IN * HID; i += 256) Ws[i] = W1[i];
    __syncthreads();
    int lane = tid & 63;
    int wv   = tid >> 6;
    float bias = b1[lane];
    int row0 = blockIdx.x * 16;
    for (int it = 0; it < 4; ++it) {
        int r = row0 + it * 4 + wv;
        if (r >= N_NODES) return;
        float xa = x[(size_t)r * F_IN + lane];
        float xb = x[(size_t)r * F_IN + 64 + lane];
        float acc = bias;
        #pragma unroll
        for (int k = 0; k < 64; ++k)
            acc += __shfl(xa, k, 64) * Ws[k * HID + lane];
        #pragma unroll
        for (int k = 0; k < 64; ++k)
            acc += __shfl(xb, k, 64) * Ws[(64 + k) * HID + lane];
        out[(size_t)r * HID + lane] = fmaxf(acc, 0.f);
    }
}

// ---------------------------------------------------------------------------
// h = (optional relu(in+bias_in)) @ Wc ; a_s = h@att_src ; a_d = h@att_dst
// One wave per row. Wc in LDS (16 KB). Attention dots fused via wave reduce.
// ---------------------------------------------------------------------------
template <bool APPLY_BIAS_RELU>
__global__ __launch_bounds__(256) void k_gemm_att(const float* __restrict__ hin,
        const float* __restrict__ Wc, const float* __restrict__ bias_in,
        const float* __restrict__ att_s, const float* __restrict__ att_d,
        float* __restrict__ h, float* __restrict__ as_, float* __restrict__ ad_) {
    __shared__ float Ws[HID * HID];           // 16 KB
    int tid = threadIdx.x;
    for (int i = tid; i < HID * HID; i += 256) Ws[i] = Wc[i];
    __syncthreads();
    int lane = tid & 63;
    int wv   = tid >> 6;
    float asv = att_s[lane];
    float adv = att_d[lane];
    float bin = APPLY_BIAS_RELU ? bias_in[lane] : 0.f;
    int row0 = blockIdx.x * 16;
    for (int it = 0; it < 4; ++it) {
        int r = row0 + it * 4 + wv;
        if (r >= N_NODES) return;
        float xv = hin[(size_t)r * HID + lane];
        if (APPLY_BIAS_RELU) xv = fmaxf(xv + bin, 0.f);
        float acc = 0.f;
        #pragma unroll
        for (int k = 0; k < 64; ++k)
            acc += __shfl(xv, k, 64) * Ws[k * HID + lane];
        h[(size_t)r * HID + lane] = acc;
        float s1 = acc * asv;
        float s2 = acc * adv;
        #pragma unroll
        for (int off = 32; off > 0; off >>= 1) {
            s1 += __shfl_xor(s1, off, 64);
            s2 += __shfl_xor(s2, off, 64);
        }
        if (lane == 0) { as_[r] = s1; ad_[r] = s2; }
    }
}

// ---------------------------------------------------------------------------
// Edge pass 1: exv[i] = exp(leaky_relu(as[src]+ad[dst])); denom[dst] += exv.
// Max-shift skipped: alpha is shift-invariant; e is O(+-10), no overflow.
// Self-loops are edges [E, E+N) with src=dst=i-E.
// ---------------------------------------------------------------------------
__global__ __launch_bounds__(256) void k_edge1(const int* __restrict__ ei,
        const float* __restrict__ as_, const float* __restrict__ ad_,
        float* __restrict__ exv, float* __restrict__ denom) {
    int i = blockIdx.x * 256 + threadIdx.x;
    const int ET = N_EDGES + N_NODES;
    if (i >= ET) return;
    int s, d;
    if (i < N_EDGES) { s = ei[i]; d = ei[N_EDGES + i]; }
    else             { s = d = i - N_EDGES; }
    float e = as_[s] + ad_[d];
    e = (e > 0.f) ? e : NEG_SLOPE * e;
    float ex = __expf(e);
    exv[i] = ex;
    atomicAdd(&denom[d], ex);
}

// ---------------------------------------------------------------------------
// Edge pass 2: agg[dst] += h[src] * (exv[i] / (denom[dst]+1e-16)).
// One wave per edge, lane = channel. Coalesced 256 B gather + atomic scatter.
// ---------------------------------------------------------------------------
__global__ __launch_bounds__(256) void k_edge2(const int* __restrict__ ei,
        const float* __restrict__ h, const float* __restrict__ exv,
        const float* __restrict__ denom, float* __restrict__ agg) {
    int lane = threadIdx.x & 63;
    int i = blockIdx.x * 4 + (threadIdx.x >> 6);
    const int ET = N_EDGES + N_NODES;
    if (i >= ET) return;
    int s, d;
    if (i < N_EDGES) { s = ei[i]; d = ei[N_EDGES + i]; }
    else             { s = d = i - N_EDGES; }
    float alpha = exv[i] / (denom[d] + 1e-16f);
    float v = h[(size_t)s * HID + lane] * alpha;
    atomicAdd(&agg[(size_t)d * HID + lane], v);
}

// ---------------------------------------------------------------------------
// logits = (agg + bias1) @ W2 + b2 ; out = log_softmax(logits)
// One wave per row; lanes 0..39 hold logits; wave-reduce max & sum.
// ---------------------------------------------------------------------------
__global__ __launch_bounds__(256) void k_final(const float* __restrict__ agg,
        const float* __restrict__ bias1, const float* __restrict__ W2,
        const float* __restrict__ b2, float* __restrict__ out) {
    __shared__ float Ws[HID * N_CLASS];       // 10 KB
    __shared__ float b2s[N_CLASS];
    int tid = threadIdx.x;
    for (int i = tid; i < HID * N_CLASS; i += 256) Ws[i] = W2[i];
    if (tid < N_CLASS) b2s[tid] = b2[tid];
    __syncthreads();
    int lane = tid & 63;
    int wv   = tid >> 6;
    float bin = bias1[lane];
    int row0 = blockIdx.x * 16;
    for (int it = 0; it < 4; ++it) {
        int r = row0 + it * 4 + wv;
        if (r >= N_NODES) return;
        float v = agg[(size_t)r * HID + lane] + bin;
        float acc = (lane < N_CLASS) ? b2s[lane] : 0.f;
        #pragma unroll
        for (int k = 0; k < 64; ++k) {
            float vk = __shfl(v, k, 64);
            if (lane < N_CLASS) acc += vk * Ws[k * N_CLASS + lane];
        }
        float mval = (lane < N_CLASS) ? acc : -INFINITY;
        #pragma unroll
        for (int off = 32; off > 0; off >>= 1)
            mval = fmaxf(mval, __shfl_xor(mval, off, 64));
        float ex = (lane < N_CLASS) ? __expf(acc - mval) : 0.f;
        float ssum = ex;
        #pragma unroll
        for (int off = 32; off > 0; off >>= 1)
            ssum += __shfl_xor(ssum, off, 64);
        if (lane < N_CLASS)
            out[(size_t)r * N_CLASS + lane] = acc - mval - logf(ssum);
    }
}

// ---------------------------------------------------------------------------
extern "C" void kernel_launch(void* const* d_in, const int* in_sizes, int n_in,
                              void* d_out, int out_size, void* d_ws, size_t ws_size,
                              hipStream_t stream) {
    const float* x     = (const float*)d_in[0];
    const int*   ei    = (const int*)  d_in[1];
    const float* W1    = (const float*)d_in[2];
    const float* b1    = (const float*)d_in[3];
    const float* Wc0   = (const float*)d_in[4];
    const float* as0   = (const float*)d_in[5];
    const float* ad0   = (const float*)d_in[6];
    const float* bias0 = (const float*)d_in[7];
    const float* Wc1   = (const float*)d_in[8];
    const float* as1   = (const float*)d_in[9];
    const float* ad1   = (const float*)d_in[10];
    const float* bias1 = (const float*)d_in[11];
    const float* W2    = (const float*)d_in[12];
    const float* b2    = (const float*)d_in[13];
    float* out = (float*)d_out;

    // Workspace layout (floats): 2 big node buffers + small arrays = ~59 MB
    float* buf_h = (float*)d_ws;                      // N*64
    float* buf_g = buf_h + (size_t)N_NODES * HID;     // N*64
    float* as_   = buf_g + (size_t)N_NODES * HID;     // N
    float* ad_   = as_ + N_NODES;                     // N
    float* denom = ad_ + N_NODES;                     // N
    float* exv   = denom + N_NODES;                   // E+N

    const int ET = N_EDGES + N_NODES;
    const int GEMM_BLOCKS  = (N_NODES + 15) / 16;     // 6250
    const int EDGE1_BLOCKS = (ET + 255) / 256;
    const int EDGE2_BLOCKS = (ET + 3) / 4;

    // h0 = relu(x@W1+b1) -> buf_h
    k_lin1<<<GEMM_BLOCKS, 256, 0, stream>>>(x, W1, b1, buf_h);

    // ---- GAT layer 0 ----
    k_gemm_att<false><<<GEMM_BLOCKS, 256, 0, stream>>>(buf_h, Wc0, bias0, as0, ad0,
                                                       buf_g, as_, ad_);
    hipMemsetAsync(denom, 0, N_NODES * sizeof(float), stream);
    k_edge1<<<EDGE1_BLOCKS, 256, 0, stream>>>(ei, as_, ad_, exv, denom);
    hipMemsetAsync(buf_h, 0, (size_t)N_NODES * HID * sizeof(float), stream);
    k_edge2<<<EDGE2_BLOCKS, 256, 0, stream>>>(ei, buf_g, exv, denom, buf_h);
    // buf_h = agg0 (pre-bias, pre-relu)

    // ---- GAT layer 1 ---- (bias0+relu applied at read)
    k_gemm_att<true><<<GEMM_BLOCKS, 256, 0, stream>>>(buf_h, Wc1, bias0, as1, ad1,
                                                      buf_g, as_, ad_);
    hipMemsetAsync(denom, 0, N_NODES * sizeof(float), stream);
    k_edge1<<<EDGE1_BLOCKS, 256, 0, stream>>>(ei, as_, ad_, exv, denom);
    hipMemsetAsync(buf_h, 0, (size_t)N_NODES * HID * sizeof(float), stream);
    k_edge2<<<EDGE2_BLOCKS, 256, 0, stream>>>(ei, buf_g, exv, denom, buf_h);
    // buf_h = agg1 (pre-bias)

    // logits + log_softmax
    k_final<<<GEMM_BLOCKS, 256, 0, stream>>>(buf_h, bias1, W2, b2, out);
}

// Round 2
// 1213.851 us; speedup vs baseline: 1.2685x; 1.2685x over previous
//
#include <hip/hip_runtime.h>

#define N_NODES 100000
#define N_EDGES 1600000
#define F_IN    128
#define HID     64
#define N_CLASS 40
#define NEG_SLOPE 0.2f
#define ET (N_EDGES + N_NODES)

// ---------------------------------------------------------------------------
// h0 = relu(x @ W1 + b1)   [N,128] @ [128,64]. One wave per row.
// ---------------------------------------------------------------------------
__global__ __launch_bounds__(256) void k_lin1(const float* __restrict__ x,
        const float* __restrict__ W1, const float* __restrict__ b1,
        float* __restrict__ out) {
    __shared__ float Ws[F_IN * HID];          // 32 KB
    int tid = threadIdx.x;
    for (int i = tid; i < F_IN * HID; i += 256) Ws[i] = W1[i];
    __syncthreads();
    int lane = tid & 63;
    int wv   = tid >> 6;
    float bias = b1[lane];
    int row0 = blockIdx.x * 16;
    for (int it = 0; it < 4; ++it) {
        int r = row0 + it * 4 + wv;
        if (r >= N_NODES) return;
        float xa = x[(size_t)r * F_IN + lane];
        float xb = x[(size_t)r * F_IN + 64 + lane];
        float acc = bias;
        #pragma unroll
        for (int k = 0; k < 64; ++k)
            acc += __shfl(xa, k, 64) * Ws[k * HID + lane];
        #pragma unroll
        for (int k = 0; k < 64; ++k)
            acc += __shfl(xb, k, 64) * Ws[(64 + k) * HID + lane];
        out[(size_t)r * HID + lane] = fmaxf(acc, 0.f);
    }
}

// ---------------------------------------------------------------------------
// h = (optional relu(in+bias_in)) @ Wc ; a_s = h@att_src ; a_d = h@att_dst
// ---------------------------------------------------------------------------
template <bool APPLY_BIAS_RELU>
__global__ __launch_bounds__(256) void k_gemm_att(const float* __restrict__ hin,
        const float* __restrict__ Wc, const float* __restrict__ bias_in,
        const float* __restrict__ att_s, const float* __restrict__ att_d,
        float* __restrict__ h, float* __restrict__ as_, float* __restrict__ ad_) {
    __shared__ float Ws[HID * HID];           // 16 KB
    int tid = threadIdx.x;
    for (int i = tid; i < HID * HID; i += 256) Ws[i] = Wc[i];
    __syncthreads();
    int lane = tid & 63;
    int wv   = tid >> 6;
    float asv = att_s[lane];
    float adv = att_d[lane];
    float bin = APPLY_BIAS_RELU ? bias_in[lane] : 0.f;
    int row0 = blockIdx.x * 16;
    for (int it = 0; it < 4; ++it) {
        int r = row0 + it * 4 + wv;
        if (r >= N_NODES) return;
        float xv = hin[(size_t)r * HID + lane];
        if (APPLY_BIAS_RELU) xv = fmaxf(xv + bin, 0.f);
        float acc = 0.f;
        #pragma unroll
        for (int k = 0; k < 64; ++k)
            acc += __shfl(xv, k, 64) * Ws[k * HID + lane];
        h[(size_t)r * HID + lane] = acc;
        float s1 = acc * asv;
        float s2 = acc * adv;
        #pragma unroll
        for (int off = 32; off > 0; off >>= 1) {
            s1 += __shfl_xor(s1, off, 64);
            s2 += __shfl_xor(s2, off, 64);
        }
        if (lane == 0) { as_[r] = s1; ad_[r] = s2; }
    }
}

// ---------------------------------------------------------------------------
// CSR build: degree histogram -> exclusive scan -> scatter src ids by dst.
// Self-loops are edges [E, E+N) with src=dst=i-E. Built once, used twice.
// ---------------------------------------------------------------------------
__global__ __launch_bounds__(256) void k_deg(const int* __restrict__ ei,
        int* __restrict__ deg) {
    int i = blockIdx.x * 256 + threadIdx.x;
    if (i >= ET) return;
    int d = (i < N_EDGES) ? ei[N_EDGES + i] : i - N_EDGES;
    atomicAdd(&deg[d], 1);
}

__global__ __launch_bounds__(1024) void k_scan(const int* __restrict__ deg,
        int* __restrict__ rowptr) {
    __shared__ int part[1024];
    int t = threadIdx.x;
    const int CH = (N_NODES + 1023) / 1024;   // 98
    int b = t * CH;
    int s = 0;
    for (int i = 0; i < CH; ++i) {
        int idx = b + i;
        if (idx < N_NODES) s += deg[idx];
    }
    part[t] = s;
    __syncthreads();
    for (int off = 1; off < 1024; off <<= 1) {
        int u = (t >= off) ? part[t - off] : 0;
        __syncthreads();
        part[t] += u;
        __syncthreads();
    }
    int base = (t == 0) ? 0 : part[t - 1];
    for (int i = 0; i < CH; ++i) {
        int idx = b + i;
        if (idx < N_NODES) { rowptr[idx] = base; base += deg[idx]; }
    }
    if (t == 1023) rowptr[N_NODES] = part[1023];
}

__global__ __launch_bounds__(256) void k_scatter(const int* __restrict__ ei,
        int* __restrict__ wp, int* __restrict__ col) {
    int i = blockIdx.x * 256 + threadIdx.x;
    if (i >= ET) return;
    int s, d;
    if (i < N_EDGES) { s = ei[i]; d = ei[N_EDGES + i]; }
    else             { s = d = i - N_EDGES; }
    int pos = atomicAdd(&wp[d], 1);
    col[pos] = s;
}

// ---------------------------------------------------------------------------
// Fused GAT aggregate: one wave per dst node; lane = channel.
// agg[d] = sum_e w_e * h[src_e] / sum_e w_e,  w_e = exp(lrelu(as[s]+ad[d])).
// (softmax normalization folded into one pass; max-shift skipped: shift-
//  invariant and e is O(10) so no overflow in f32.)
// Chunk-load 64 edge ids + weights lane-parallel (coalesced), then broadcast.
// ---------------------------------------------------------------------------
__global__ __launch_bounds__(256) void k_gat_agg(const int* __restrict__ rowptr,
        const int* __restrict__ col, const float* __restrict__ h,
        const float* __restrict__ as_, const float* __restrict__ ad_,
        float* __restrict__ outagg) {
    int lane = threadIdx.x & 63;
    int d = blockIdx.x * 4 + (threadIdx.x >> 6);
    if (d >= N_NODES) return;
    int beg = rowptr[d], end = rowptr[d + 1];
    float add = ad_[d];
    float acc = 0.f, den = 0.f;
    for (int c = beg; c < end; c += 64) {
        int n = end - c;
        int sj = 0; float wj = 0.f;
        if (lane < n) {
            sj = col[c + lane];
            float e = as_[sj] + add;
            e = (e > 0.f) ? e : NEG_SLOPE * e;
            wj = __expf(e);
        }
        int m = (n < 64) ? n : 64;
        for (int j = 0; j < m; ++j) {
            int s   = __shfl(sj, j, 64);
            float w = __shfl(wj, j, 64);
            den += w;
            acc += w * h[(size_t)s * HID + lane];
        }
    }
    outagg[(size_t)d * HID + lane] = acc / (den + 1e-16f);
}

// ---------------------------------------------------------------------------
// logits = (agg + bias1) @ W2 + b2 ; out = log_softmax(logits)
// ---------------------------------------------------------------------------
__global__ __launch_bounds__(256) void k_final(const float* __restrict__ agg,
        const float* __restrict__ bias1, const float* __restrict__ W2,
        const float* __restrict__ b2, float* __restrict__ out) {
    __shared__ float Ws[HID * N_CLASS];       // 10 KB
    __shared__ float b2s[N_CLASS];
    int tid = threadIdx.x;
    for (int i = tid; i < HID * N_CLASS; i += 256) Ws[i] = W2[i];
    if (tid < N_CLASS) b2s[tid] = b2[tid];
    __syncthreads();
    int lane = tid & 63;
    int wv   = tid >> 6;
    float bin = bias1[lane];
    int row0 = blockIdx.x * 16;
    for (int it = 0; it < 4; ++it) {
        int r = row0 + it * 4 + wv;
        if (r >= N_NODES) return;
        float v = agg[(size_t)r * HID + lane] + bin;
        float acc = (lane < N_CLASS) ? b2s[lane] : 0.f;
        #pragma unroll
        for (int k = 0; k < 64; ++k) {
            float vk = __shfl(v, k, 64);
            if (lane < N_CLASS) acc += vk * Ws[k * N_CLASS + lane];
        }
        float mval = (lane < N_CLASS) ? acc : -INFINITY;
        #pragma unroll
        for (int off = 32; off > 0; off >>= 1)
            mval = fmaxf(mval, __shfl_xor(mval, off, 64));
        float ex = (lane < N_CLASS) ? __expf(acc - mval) : 0.f;
        float ssum = ex;
        #pragma unroll
        for (int off = 32; off > 0; off >>= 1)
            ssum += __shfl_xor(ssum, off, 64);
        if (lane < N_CLASS)
            out[(size_t)r * N_CLASS + lane] = acc - mval - logf(ssum);
    }
}

// ---------------------------------------------------------------------------
extern "C" void kernel_launch(void* const* d_in, const int* in_sizes, int n_in,
                              void* d_out, int out_size, void* d_ws, size_t ws_size,
                              hipStream_t stream) {
    const float* x     = (const float*)d_in[0];
    const int*   ei    = (const int*)  d_in[1];
    const float* W1    = (const float*)d_in[2];
    const float* b1    = (const float*)d_in[3];
    const float* Wc0   = (const float*)d_in[4];
    const float* as0   = (const float*)d_in[5];
    const float* ad0   = (const float*)d_in[6];
    const float* bias0 = (const float*)d_in[7];
    const float* Wc1   = (const float*)d_in[8];
    const float* as1   = (const float*)d_in[9];
    const float* ad1   = (const float*)d_in[10];
    const float* bias1 = (const float*)d_in[11];
    const float* W2    = (const float*)d_in[12];
    const float* b2    = (const float*)d_in[13];
    float* out = (float*)d_out;

    // Workspace layout: 2 big node buffers + attention scalars + CSR (~60 MB)
    float* buf_h  = (float*)d_ws;                      // N*64 f
    float* buf_g  = buf_h + (size_t)N_NODES * HID;     // N*64 f
    float* as_    = buf_g + (size_t)N_NODES * HID;     // N f
    float* ad_    = as_ + N_NODES;                     // N f
    int*   deg    = (int*)(ad_ + N_NODES);             // N i (reused as wp)
    int*   rowptr = deg + N_NODES;                     // N+1 i
    int*   col    = rowptr + (N_NODES + 1);            // ET i

    const int GEMM_BLOCKS = (N_NODES + 15) / 16;      // 6250
    const int EDGE_BLOCKS = (ET + 255) / 256;
    const int AGG_BLOCKS  = (N_NODES + 3) / 4;

    // ---- CSR build (once; reused by both layers) ----
    hipMemsetAsync(deg, 0, N_NODES * sizeof(int), stream);
    k_deg<<<EDGE_BLOCKS, 256, 0, stream>>>(ei, deg);
    k_scan<<<1, 1024, 0, stream>>>(deg, rowptr);
    // deg's buffer now becomes the scatter write-pointer array wp
    hipMemcpyAsync(deg, rowptr, N_NODES * sizeof(int),
                   hipMemcpyDeviceToDevice, stream);
    k_scatter<<<EDGE_BLOCKS, 256, 0, stream>>>(ei, deg, col);

    // h0 = relu(x@W1+b1) -> buf_h
    k_lin1<<<GEMM_BLOCKS, 256, 0, stream>>>(x, W1, b1, buf_h);

    // ---- GAT layer 0 ----
    k_gemm_att<false><<<GEMM_BLOCKS, 256, 0, stream>>>(buf_h, Wc0, bias0, as0, ad0,
                                                       buf_g, as_, ad_);
    k_gat_agg<<<AGG_BLOCKS, 256, 0, stream>>>(rowptr, col, buf_g, as_, ad_, buf_h);

    // ---- GAT layer 1 ---- (bias0+relu applied at read)
    k_gemm_att<true><<<GEMM_BLOCKS, 256, 0, stream>>>(buf_h, Wc1, bias0, as1, ad1,
                                                      buf_g, as_, ad_);
    k_gat_agg<<<AGG_BLOCKS, 256, 0, stream>>>(rowptr, col, buf_g, as_, ad_, buf_h);

    // logits + log_softmax
    k_final<<<GEMM_BLOCKS, 256, 0, stream>>>(buf_h, bias1, W2, b2, out);
}

// Round 3
// 787.257 us; speedup vs baseline: 1.9558x; 1.5419x over previous
//
#include <hip/hip_runtime.h>

#define N_NODES 100000
#define N_EDGES 1600000
#define F_IN    128
#define HID     64
#define N_CLASS 40
#define NEG_SLOPE 0.2f
#define ET (N_EDGES + N_NODES)
#define NBLK ((N_NODES + 255) / 256)   // 391 scan blocks

// ---------------------------------------------------------------------------
// h0 = relu(x @ W1 + b1). Lane holds W1[:,lane] in 128 VGPRs; x-row read as
// wave-uniform float4 broadcasts; inner loop = pure v_fmac (no LDS pipe).
// Each wave processes 8 rows so the W-register load amortizes.
// ---------------------------------------------------------------------------
__global__ __launch_bounds__(256) void k_lin1(const float* __restrict__ x,
        const float* __restrict__ W1, const float* __restrict__ b1,
        float* __restrict__ out) {
    int lane = threadIdx.x & 63;
    int wid  = blockIdx.x * 4 + (threadIdx.x >> 6);
    float wcol[F_IN];
    #pragma unroll
    for (int k = 0; k < F_IN; ++k) wcol[k] = W1[k * HID + lane];
    float bias = b1[lane];
    int r0 = wid * 8;
    #pragma unroll
    for (int i = 0; i < 8; ++i) {
        int r = r0 + i;
        if (r >= N_NODES) return;
        const float4* xr = (const float4*)(x + (size_t)r * F_IN);
        float a0 = bias, a1 = 0.f, a2 = 0.f, a3 = 0.f;
        #pragma unroll
        for (int q = 0; q < F_IN / 4; ++q) {
            float4 xv = xr[q];
            a0 = fmaf(xv.x, wcol[4 * q + 0], a0);
            a1 = fmaf(xv.y, wcol[4 * q + 1], a1);
            a2 = fmaf(xv.z, wcol[4 * q + 2], a2);
            a3 = fmaf(xv.w, wcol[4 * q + 3], a3);
        }
        out[(size_t)r * HID + lane] = fmaxf((a0 + a1) + (a2 + a3), 0.f);
    }
}

// ---------------------------------------------------------------------------
// h = hin @ Wc ; as_ = h@att_src ; ad_ = h@att_dst.  (hin is already
// bias+relu'd by the producer.)  Register-W, uniform float4 x loads.
// ---------------------------------------------------------------------------
__global__ __launch_bounds__(256) void k_gemm_att(const float* __restrict__ hin,
        const float* __restrict__ Wc,
        const float* __restrict__ att_s, const float* __restrict__ att_d,
        float* __restrict__ h, float* __restrict__ as_, float* __restrict__ ad_) {
    int lane = threadIdx.x & 63;
    int wid  = blockIdx.x * 4 + (threadIdx.x >> 6);
    float wcol[HID];
    #pragma unroll
    for (int k = 0; k < HID; ++k) wcol[k] = Wc[k * HID + lane];
    float asv = att_s[lane];
    float adv = att_d[lane];
    int r0 = wid * 8;
    #pragma unroll
    for (int i = 0; i < 8; ++i) {
        int r = r0 + i;
        if (r >= N_NODES) return;
        const float4* xr = (const float4*)(hin + (size_t)r * HID);
        float a0 = 0.f, a1 = 0.f, a2 = 0.f, a3 = 0.f;
        #pragma unroll
        for (int q = 0; q < HID / 4; ++q) {
            float4 xv = xr[q];
            a0 = fmaf(xv.x, wcol[4 * q + 0], a0);
            a1 = fmaf(xv.y, wcol[4 * q + 1], a1);
            a2 = fmaf(xv.z, wcol[4 * q + 2], a2);
            a3 = fmaf(xv.w, wcol[4 * q + 3], a3);
        }
        float acc = (a0 + a1) + (a2 + a3);
        h[(size_t)r * HID + lane] = acc;
        float s1 = acc * asv;
        float s2 = acc * adv;
        #pragma unroll
        for (int off = 32; off > 0; off >>= 1) {
            s1 += __shfl_xor(s1, off, 64);
            s2 += __shfl_xor(s2, off, 64);
        }
        if (lane == 0) { as_[r] = s1; ad_[r] = s2; }
    }
}

// ---------------------------------------------------------------------------
// CSR build: degree histogram -> hierarchical scan -> scatter.
// ---------------------------------------------------------------------------
__global__ __launch_bounds__(256) void k_deg(const int* __restrict__ ei,
        int* __restrict__ deg) {
    int i = blockIdx.x * 256 + threadIdx.x;
    if (i >= ET) return;
    int d = (i < N_EDGES) ? ei[N_EDGES + i] : i - N_EDGES;
    atomicAdd(&deg[d], 1);
}

__global__ __launch_bounds__(256) void k_bsum(const int* __restrict__ deg,
        int* __restrict__ bsum) {
    __shared__ int s[256];
    int t = threadIdx.x, i = blockIdx.x * 256 + t;
    s[t] = (i < N_NODES) ? deg[i] : 0;
    __syncthreads();
    for (int off = 128; off > 0; off >>= 1) {
        if (t < off) s[t] += s[t + off];
        __syncthreads();
    }
    if (t == 0) bsum[blockIdx.x] = s[0];
}

__global__ __launch_bounds__(512) void k_bscan(const int* __restrict__ bsum,
        int* __restrict__ bbase) {
    __shared__ int s[512];
    int t = threadIdx.x;
    int v = (t < NBLK) ? bsum[t] : 0;
    s[t] = v; __syncthreads();
    for (int off = 1; off < 512; off <<= 1) {
        int u = (t >= off) ? s[t - off] : 0;
        __syncthreads();
        s[t] += u;
        __syncthreads();
    }
    if (t < NBLK) bbase[t] = s[t] - v;   // exclusive
}

__global__ __launch_bounds__(256) void k_rowptr(const int* __restrict__ deg,
        const int* __restrict__ bbase, int* __restrict__ rowptr) {
    __shared__ int s[256];
    int t = threadIdx.x, i = blockIdx.x * 256 + t;
    int v = (i < N_NODES) ? deg[i] : 0;
    s[t] = v; __syncthreads();
    for (int off = 1; off < 256; off <<= 1) {
        int u = (t >= off) ? s[t - off] : 0;
        __syncthreads();
        s[t] += u;
        __syncthreads();
    }
    if (i < N_NODES) rowptr[i] = bbase[blockIdx.x] + s[t] - v;
    if (i == 0) rowptr[N_NODES] = ET;
}

__global__ __launch_bounds__(256) void k_scatter(const int* __restrict__ ei,
        int* __restrict__ wp, int* __restrict__ col) {
    int i = blockIdx.x * 256 + threadIdx.x;
    if (i >= ET) return;
    int s, d;
    if (i < N_EDGES) { s = ei[i]; d = ei[N_EDGES + i]; }
    else             { s = d = i - N_EDGES; }
    int pos = atomicAdd(&wp[d], 1);
    col[pos] = s;
}

// ---------------------------------------------------------------------------
// Fused GAT aggregate, float4-slot layout: one wave per dst node; 4 edge
// slots x 16 lanes; lane (slot=lane>>4) holds channels (lane&15)*4..+3.
// Per iteration: 4 edges gathered as float4 (1 KB/instr). Softmax
// normalization folded in (denominator accumulated alongside).
// Epilogue: cross-slot shfl_xor reduce, then out = acc/den + bias [relu].
// ---------------------------------------------------------------------------
template <bool RELU>
__global__ __launch_bounds__(256) void k_gat_agg(const int* __restrict__ rowptr,
        const int* __restrict__ col, const float* __restrict__ h,
        const float* __restrict__ as_, const float* __restrict__ ad_,
        const float* __restrict__ bias, float* __restrict__ outagg) {
    int lane = threadIdx.x & 63;
    int d = blockIdx.x * 4 + (threadIdx.x >> 6);
    if (d >= N_NODES) return;
    int slot = lane >> 4;
    int ch   = (lane & 15) * 4;
    int beg = rowptr[d], end = rowptr[d + 1];
    float add = ad_[d];
    float ax = 0.f, ay = 0.f, az = 0.f, aw = 0.f, den = 0.f;
    for (int c = beg; c < end; c += 64) {
        int n = end - c;
        int sj = 0; float wj = 0.f;
        if (lane < n) {
            sj = col[c + lane];
            float e = as_[sj] + add;
            e = (e > 0.f) ? e : NEG_SLOPE * e;
            wj = __expf(e);
        }
        int m = (n < 64) ? n : 64;
        int iters = (m + 3) >> 2;
        for (int j = 0; j < iters; ++j) {
            int sl = j * 4 + slot;
            int   s = __shfl(sj, sl, 64);
            float w = __shfl(wj, sl, 64);   // 0 for out-of-range slots
            den += w;
            const float4 hv = *(const float4*)(h + (size_t)s * HID + ch);
            ax = fmaf(w, hv.x, ax);
            ay = fmaf(w, hv.y, ay);
            az = fmaf(w, hv.z, az);
            aw = fmaf(w, hv.w, aw);
        }
    }
    // reduce the 4 slots (lanes l, l^16, l^32, l^48 hold the same channels)
    #pragma unroll
    for (int off = 16; off <= 32; off <<= 1) {
        ax  += __shfl_xor(ax,  off, 64);
        ay  += __shfl_xor(ay,  off, 64);
        az  += __shfl_xor(az,  off, 64);
        aw  += __shfl_xor(aw,  off, 64);
        den += __shfl_xor(den, off, 64);
    }
    if (slot == 0) {
        float inv = 1.f / (den + 1e-16f);
        const float4 bv = *(const float4*)(bias + ch);
        float4 o;
        o.x = ax * inv + bv.x;
        o.y = ay * inv + bv.y;
        o.z = az * inv + bv.z;
        o.w = aw * inv + bv.w;
        if (RELU) {
            o.x = fmaxf(o.x, 0.f); o.y = fmaxf(o.y, 0.f);
            o.z = fmaxf(o.z, 0.f); o.w = fmaxf(o.w, 0.f);
        }
        *(float4*)(outagg + (size_t)d * HID + ch) = o;
    }
}

// ---------------------------------------------------------------------------
// logits = agg @ W2 + b2 ; out = log_softmax.  (agg already has bias1.)
// Register-W: lane<40 holds W2[:,lane].
// ---------------------------------------------------------------------------
__global__ __launch_bounds__(256) void k_final(const float* __restrict__ agg,
        const float* __restrict__ W2, const float* __restrict__ b2,
        float* __restrict__ out) {
    int lane = threadIdx.x & 63;
    int wid  = blockIdx.x * 4 + (threadIdx.x >> 6);
    float wcol[HID];
    #pragma unroll
    for (int k = 0; k < HID; ++k)
        wcol[k] = (lane < N_CLASS) ? W2[k * N_CLASS + lane] : 0.f;
    float bias = (lane < N_CLASS) ? b2[lane] : 0.f;
    int r0 = wid * 8;
    #pragma unroll
    for (int i = 0; i < 8; ++i) {
        int r = r0 + i;
        if (r >= N_NODES) return;
        const float4* xr = (const float4*)(agg + (size_t)r * HID);
        float a0 = bias, a1 = 0.f, a2 = 0.f, a3 = 0.f;
        #pragma unroll
        for (int q = 0; q < HID / 4; ++q) {
            float4 xv = xr[q];
            a0 = fmaf(xv.x, wcol[4 * q + 0], a0);
            a1 = fmaf(xv.y, wcol[4 * q + 1], a1);
            a2 = fmaf(xv.z, wcol[4 * q + 2], a2);
            a3 = fmaf(xv.w, wcol[4 * q + 3], a3);
        }
        float acc = (a0 + a1) + (a2 + a3);
        float mval = (lane < N_CLASS) ? acc : -INFINITY;
        #pragma unroll
        for (int off = 32; off > 0; off >>= 1)
            mval = fmaxf(mval, __shfl_xor(mval, off, 64));
        float ex = (lane < N_CLASS) ? __expf(acc - mval) : 0.f;
        float ssum = ex;
        #pragma unroll
        for (int off = 32; off > 0; off >>= 1)
            ssum += __shfl_xor(ssum, off, 64);
        if (lane < N_CLASS)
            out[(size_t)r * N_CLASS + lane] = acc - mval - logf(ssum);
    }
}

// ---------------------------------------------------------------------------
extern "C" void kernel_launch(void* const* d_in, const int* in_sizes, int n_in,
                              void* d_out, int out_size, void* d_ws, size_t ws_size,
                              hipStream_t stream) {
    const float* x     = (const float*)d_in[0];
    const int*   ei    = (const int*)  d_in[1];
    const float* W1    = (const float*)d_in[2];
    const float* b1    = (const float*)d_in[3];
    const float* Wc0   = (const float*)d_in[4];
    const float* as0   = (const float*)d_in[5];
    const float* ad0   = (const float*)d_in[6];
    const float* bias0 = (const float*)d_in[7];
    const float* Wc1   = (const float*)d_in[8];
    const float* as1   = (const float*)d_in[9];
    const float* ad1   = (const float*)d_in[10];
    const float* bias1 = (const float*)d_in[11];
    const float* W2    = (const float*)d_in[12];
    const float* b2    = (const float*)d_in[13];
    float* out = (float*)d_out;

    // Workspace layout
    float* buf_h  = (float*)d_ws;                      // N*64 f
    float* buf_g  = buf_h + (size_t)N_NODES * HID;     // N*64 f
    float* as_    = buf_g + (size_t)N_NODES * HID;     // N f
    float* ad_    = as_ + N_NODES;                     // N f
    int*   deg    = (int*)(ad_ + N_NODES);             // N i (reused as wp)
    int*   rowptr = deg + N_NODES;                     // N+1 i
    int*   col    = rowptr + (N_NODES + 1);            // ET i
    int*   bsum   = col + ET;                          // NBLK i
    int*   bbase  = bsum + NBLK;                       // NBLK i

    const int ROW_BLOCKS  = 3125;                      // 12500 waves x 8 rows
    const int EDGE_BLOCKS = (ET + 255) / 256;
    const int AGG_BLOCKS  = (N_NODES + 3) / 4;

    // ---- CSR build (once; reused by both layers) ----
    hipMemsetAsync(deg, 0, N_NODES * sizeof(int), stream);
    k_deg<<<EDGE_BLOCKS, 256, 0, stream>>>(ei, deg);
    k_bsum<<<NBLK, 256, 0, stream>>>(deg, bsum);
    k_bscan<<<1, 512, 0, stream>>>(bsum, bbase);
    k_rowptr<<<NBLK, 256, 0, stream>>>(deg, bbase, rowptr);
    hipMemcpyAsync(deg, rowptr, N_NODES * sizeof(int),
                   hipMemcpyDeviceToDevice, stream);   // deg -> wp
    k_scatter<<<EDGE_BLOCKS, 256, 0, stream>>>(ei, deg, col);

    // h0 = relu(x@W1+b1) -> buf_h
    k_lin1<<<ROW_BLOCKS, 256, 0, stream>>>(x, W1, b1, buf_h);

    // ---- GAT layer 0 ----  (bias0 + relu fused into aggregate epilogue)
    k_gemm_att<<<ROW_BLOCKS, 256, 0, stream>>>(buf_h, Wc0, as0, ad0,
                                               buf_g, as_, ad_);
    k_gat_agg<true><<<AGG_BLOCKS, 256, 0, stream>>>(rowptr, col, buf_g,
                                                    as_, ad_, bias0, buf_h);

    // ---- GAT layer 1 ----  (bias1 fused, no relu)
    k_gemm_att<<<ROW_BLOCKS, 256, 0, stream>>>(buf_h, Wc1, as1, ad1,
                                               buf_g, as_, ad_);
    k_gat_agg<false><<<AGG_BLOCKS, 256, 0, stream>>>(rowptr, col, buf_g,
                                                     as_, ad_, bias1, buf_h);

    // logits + log_softmax
    k_final<<<ROW_BLOCKS, 256, 0, stream>>>(buf_h, W2, b2, out);
}